// Round 1
// baseline (352.281 us; speedup 1.0000x reference)
//
#include <hip/hip_runtime.h>
#include <hip/hip_bf16.h>
#include <cstdint>
#include <cstddef>

typedef __bf16 bf16_t;
typedef __bf16 bf16x8 __attribute__((ext_vector_type(8)));
typedef float f32x4 __attribute__((ext_vector_type(4)));

constexpr int B_ = 4, T_ = 2048, C_ = 768, H_ = 12, D_ = 64;
constexpr int M_ = B_ * T_;      // 8192
constexpr int NQKV_ = 3 * C_;    // 2304
constexpr size_t QKV_ELEMS = (size_t)B_ * H_ * T_ * D_;  // 6291456 per tensor

// ---------------------------------------------------------------------------
// Kernel 1: QKV GEMM.  C[m][n] = sum_k x[m][k]*w_qkv[n][k] + b[n]
// scattered into q/k/v laid out (B, H, T, D) as bf16.
// 128x128 block tile, 4 waves (2x2), K_STEP=64, LDS stride 72 (pad).
// ---------------------------------------------------------------------------
__global__ __launch_bounds__(256, 2)
void qkv_gemm(const float* __restrict__ x, const float* __restrict__ wq,
              const float* __restrict__ bias,
              bf16_t* __restrict__ q, bf16_t* __restrict__ k, bf16_t* __restrict__ v)
{
    __shared__ alignas(16) bf16_t As[128 * 72];
    __shared__ alignas(16) bf16_t Bs[128 * 72];
    const int tid  = threadIdx.x;
    const int lane = tid & 63;
    const int wid  = tid >> 6;
    const int wm = wid >> 1, wn = wid & 1;
    const int bm = blockIdx.x & 63;   // 64 m-blocks
    const int bn = blockIdx.x >> 6;   // 18 n-blocks
    const int m0 = bm * 128, n0 = bn * 128;
    const int sr = tid >> 3, sc = tid & 7;
    const int lcol = lane & 15, lgrp = lane >> 4;

    f32x4 acc[4][4] = {};

    for (int kt = 0; kt < C_; kt += 64) {
        __syncthreads();
        #pragma unroll
        for (int p = 0; p < 4; ++p) {
            const int row = p * 32 + sr;
            const float4* ga = reinterpret_cast<const float4*>(x + (size_t)(m0 + row) * C_ + kt + sc * 8);
            float4 f0 = ga[0], f1 = ga[1];
            bf16x8 ta;
            ta[0]=(bf16_t)f0.x; ta[1]=(bf16_t)f0.y; ta[2]=(bf16_t)f0.z; ta[3]=(bf16_t)f0.w;
            ta[4]=(bf16_t)f1.x; ta[5]=(bf16_t)f1.y; ta[6]=(bf16_t)f1.z; ta[7]=(bf16_t)f1.w;
            *reinterpret_cast<bf16x8*>(&As[row * 72 + sc * 8]) = ta;
            const float4* gb = reinterpret_cast<const float4*>(wq + (size_t)(n0 + row) * C_ + kt + sc * 8);
            float4 g0 = gb[0], g1 = gb[1];
            bf16x8 tb;
            tb[0]=(bf16_t)g0.x; tb[1]=(bf16_t)g0.y; tb[2]=(bf16_t)g0.z; tb[3]=(bf16_t)g0.w;
            tb[4]=(bf16_t)g1.x; tb[5]=(bf16_t)g1.y; tb[6]=(bf16_t)g1.z; tb[7]=(bf16_t)g1.w;
            *reinterpret_cast<bf16x8*>(&Bs[row * 72 + sc * 8]) = tb;
        }
        __syncthreads();
        #pragma unroll
        for (int kk = 0; kk < 2; ++kk) {
            bf16x8 af[4], bfr[4];
            #pragma unroll
            for (int i = 0; i < 4; ++i)
                af[i] = *reinterpret_cast<const bf16x8*>(&As[(wm*64 + i*16 + lcol) * 72 + kk*32 + lgrp*8]);
            #pragma unroll
            for (int j = 0; j < 4; ++j)
                bfr[j] = *reinterpret_cast<const bf16x8*>(&Bs[(wn*64 + j*16 + lcol) * 72 + kk*32 + lgrp*8]);
            #pragma unroll
            for (int i = 0; i < 4; ++i)
                #pragma unroll
                for (int j = 0; j < 4; ++j)
                    acc[i][j] = __builtin_amdgcn_mfma_f32_16x16x32_bf16(af[i], bfr[j], acc[i][j], 0, 0, 0);
        }
    }

    #pragma unroll
    for (int j = 0; j < 4; ++j) {
        const int n = n0 + wn*64 + j*16 + lcol;
        const float bv = bias[n];
        const int s = n / C_, rem = n % C_;
        const int h = rem >> 6, d = rem & 63;
        bf16_t* dst = (s == 0) ? q : (s == 1) ? k : v;
        #pragma unroll
        for (int i = 0; i < 4; ++i) {
            #pragma unroll
            for (int r = 0; r < 4; ++r) {
                const int m = m0 + wm*64 + i*16 + lgrp*4 + r;
                const int b = m >> 11, t = m & (T_ - 1);
                dst[(((size_t)(b * H_ + h)) * T_ + t) * D_ + d] = (bf16_t)(acc[i][j][r] + bv);
            }
        }
    }
}

// ---------------------------------------------------------------------------
// Kernel 2: causal flash attention. q/k/v (B,H,T,D) bf16 -> out (B,T,C) bf16.
// Block = 4 waves, each wave owns 16 q-rows (64-row Q tile per block).
// KV staged per 64-key tile: K row-major [64][72], V transposed [64][72].
// P re-layout via per-wave LDS tile [16][40].
// ---------------------------------------------------------------------------
__global__ __launch_bounds__(256, 2)
void attn_fwd(const bf16_t* __restrict__ qg, const bf16_t* __restrict__ kg,
              const bf16_t* __restrict__ vg, bf16_t* __restrict__ og)
{
    __shared__ alignas(16) bf16_t Ks[64 * 72];
    __shared__ alignas(16) bf16_t Vt[64 * 72];
    __shared__ alignas(16) bf16_t Ps[4 * 16 * 40];

    const int tid  = threadIdx.x;
    const int lane = tid & 63;
    const int w    = tid >> 6;
    const int lcol = lane & 15, lgrp = lane >> 4;
    const int qtile = blockIdx.x & 31;  // T/64 = 32
    const int bh    = blockIdx.x >> 5;  // 0..47
    const size_t base = (size_t)bh * T_ * D_;
    const int q0 = qtile * 64;
    const int qw = q0 + w * 16;

    // Q fragments, pre-scaled by 1/sqrt(D)=0.125 (power of 2 -> exact in bf16)
    bf16x8 aq[2];
    {
        const int qrow = qw + lcol;
        #pragma unroll
        for (int kk = 0; kk < 2; ++kk) {
            bf16x8 qv = *reinterpret_cast<const bf16x8*>(&qg[base + (size_t)qrow * D_ + kk*32 + lgrp*8]);
            #pragma unroll
            for (int e = 0; e < 8; ++e) qv[e] = (bf16_t)((float)qv[e] * 0.125f);
            aq[kk] = qv;
        }
    }

    f32x4 o[4] = {};
    float rowm[4], rowl[4];
    #pragma unroll
    for (int r = 0; r < 4; ++r) { rowm[r] = -1e30f; rowl[r] = 0.0f; }

    const int ntiles = (q0 >> 6) + 1;
    for (int it = 0; it < ntiles; ++it) {
        const int kv0 = it * 64;
        __syncthreads();
        // stage K tile [64][72]
        #pragma unroll
        for (int p = 0; p < 2; ++p) {
            const int row = p * 32 + (tid >> 3);
            const int cs  = tid & 7;
            *reinterpret_cast<bf16x8*>(&Ks[row * 72 + cs * 8]) =
                *reinterpret_cast<const bf16x8*>(&kg[base + (size_t)(kv0 + row) * D_ + cs * 8]);
        }
        // stage V transposed: Vt[d][key]
        {
            const int key = tid >> 2, d0 = (tid & 3) * 16;
            bf16x8 r0 = *reinterpret_cast<const bf16x8*>(&vg[base + (size_t)(kv0 + key) * D_ + d0]);
            bf16x8 r1 = *reinterpret_cast<const bf16x8*>(&vg[base + (size_t)(kv0 + key) * D_ + d0 + 8]);
            #pragma unroll
            for (int jj = 0; jj < 8; ++jj) {
                Vt[(d0 + jj) * 72 + key]     = r0[jj];
                Vt[(d0 + 8 + jj) * 72 + key] = r1[jj];
            }
        }
        __syncthreads();

        const bool diag = (kv0 == q0);
        #pragma unroll
        for (int sk = 0; sk < 2; ++sk) {
            if (kv0 + sk * 32 > qw + 15) continue;  // fully masked sub-tile (diag only)

            // S = Q K^T (pre-scaled): two 16-key fragments
            f32x4 s[2] = {};
            #pragma unroll
            for (int kk = 0; kk < 2; ++kk) {
                #pragma unroll
                for (int nf = 0; nf < 2; ++nf) {
                    bf16x8 bk = *reinterpret_cast<const bf16x8*>(
                        &Ks[(sk*32 + nf*16 + lcol) * 72 + kk*32 + lgrp*8]);
                    s[nf] = __builtin_amdgcn_mfma_f32_16x16x32_bf16(aq[kk], bk, s[nf], 0, 0, 0);
                }
            }
            if (diag) {
                #pragma unroll
                for (int nf = 0; nf < 2; ++nf) {
                    const int keyg = kv0 + sk*32 + nf*16 + lcol;
                    #pragma unroll
                    for (int r = 0; r < 4; ++r) {
                        const int qrow = qw + lgrp*4 + r;
                        if (keyg > qrow) s[nf][r] = -1e30f;
                    }
                }
            }
            // online softmax (rows live across the 16 lanes of each lane-group)
            float p0s[4], p1s[4];
            #pragma unroll
            for (int r = 0; r < 4; ++r) {
                float mx = fmaxf(s[0][r], s[1][r]);
                #pragma unroll
                for (int off = 1; off < 16; off <<= 1) mx = fmaxf(mx, __shfl_xor(mx, off));
                const float mnew  = fmaxf(rowm[r], mx);
                const float alpha = __expf(rowm[r] - mnew);
                const float p0 = __expf(s[0][r] - mnew);
                const float p1 = __expf(s[1][r] - mnew);
                float rs = p0 + p1;
                #pragma unroll
                for (int off = 1; off < 16; off <<= 1) rs += __shfl_xor(rs, off);
                rowl[r] = rowl[r] * alpha + rs;
                rowm[r] = mnew;
                #pragma unroll
                for (int nf2 = 0; nf2 < 4; ++nf2) o[nf2][r] *= alpha;
                p0s[r] = p0; p1s[r] = p1;
            }
            // P -> LDS (per-wave region), re-read as MFMA A-fragment
            bf16_t* pw = &Ps[w * 16 * 40];
            #pragma unroll
            for (int r = 0; r < 4; ++r) {
                pw[(lgrp*4 + r) * 40 + lcol]      = (bf16_t)p0s[r];
                pw[(lgrp*4 + r) * 40 + 16 + lcol] = (bf16_t)p1s[r];
            }
            bf16x8 ap = *reinterpret_cast<const bf16x8*>(&pw[lcol * 40 + lgrp * 8]);
            #pragma unroll
            for (int nf2 = 0; nf2 < 4; ++nf2) {
                bf16x8 bv = *reinterpret_cast<const bf16x8*>(
                    &Vt[(nf2*16 + lcol) * 72 + sk*32 + lgrp*8]);
                o[nf2] = __builtin_amdgcn_mfma_f32_16x16x32_bf16(ap, bv, o[nf2], 0, 0, 0);
            }
        }
    }

    // epilogue: normalize and write (B,T,C) bf16
    const int b = bh / H_, h = bh % H_;
    #pragma unroll
    for (int r = 0; r < 4; ++r) {
        const float inv = 1.0f / rowl[r];
        const int t = qw + lgrp*4 + r;
        bf16_t* dst = &og[((size_t)b * T_ + t) * C_ + h * D_];
        #pragma unroll
        for (int nf2 = 0; nf2 < 4; ++nf2)
            dst[nf2*16 + lcol] = (bf16_t)(o[nf2][r] * inv);
    }
}

// ---------------------------------------------------------------------------
// Kernel 3: output projection.  out[m][n] = sum_k ao[m][k]*w_proj[n][k] + b[n]
// ao bf16 (8192x768), w fp32 -> bf16, out fp32.
// ---------------------------------------------------------------------------
__global__ __launch_bounds__(256, 2)
void proj_gemm(const bf16_t* __restrict__ ao, const float* __restrict__ wp,
               const float* __restrict__ bias, float* __restrict__ out)
{
    __shared__ alignas(16) bf16_t As[128 * 72];
    __shared__ alignas(16) bf16_t Bs[128 * 72];
    const int tid  = threadIdx.x;
    const int lane = tid & 63;
    const int wid  = tid >> 6;
    const int wm = wid >> 1, wn = wid & 1;
    const int bm = blockIdx.x & 63;   // 64 m-blocks
    const int bn = blockIdx.x >> 6;   // 6 n-blocks
    const int m0 = bm * 128, n0 = bn * 128;
    const int lcol = lane & 15, lgrp = lane >> 4;

    f32x4 acc[4][4] = {};

    for (int kt = 0; kt < C_; kt += 64) {
        __syncthreads();
        #pragma unroll
        for (int p = 0; p < 4; ++p) {
            const int row = p * 32 + (tid >> 3);
            const int cs  = tid & 7;
            *reinterpret_cast<bf16x8*>(&As[row * 72 + cs * 8]) =
                *reinterpret_cast<const bf16x8*>(&ao[(size_t)(m0 + row) * C_ + kt + cs * 8]);
            const float4* gb = reinterpret_cast<const float4*>(wp + (size_t)(n0 + row) * C_ + kt + cs * 8);
            float4 g0 = gb[0], g1 = gb[1];
            bf16x8 tb;
            tb[0]=(bf16_t)g0.x; tb[1]=(bf16_t)g0.y; tb[2]=(bf16_t)g0.z; tb[3]=(bf16_t)g0.w;
            tb[4]=(bf16_t)g1.x; tb[5]=(bf16_t)g1.y; tb[6]=(bf16_t)g1.z; tb[7]=(bf16_t)g1.w;
            *reinterpret_cast<bf16x8*>(&Bs[row * 72 + cs * 8]) = tb;
        }
        __syncthreads();
        #pragma unroll
        for (int kk = 0; kk < 2; ++kk) {
            bf16x8 af[4], bfr[4];
            #pragma unroll
            for (int i = 0; i < 4; ++i)
                af[i] = *reinterpret_cast<const bf16x8*>(&As[(wm*64 + i*16 + lcol) * 72 + kk*32 + lgrp*8]);
            #pragma unroll
            for (int j = 0; j < 4; ++j)
                bfr[j] = *reinterpret_cast<const bf16x8*>(&Bs[(wn*64 + j*16 + lcol) * 72 + kk*32 + lgrp*8]);
            #pragma unroll
            for (int i = 0; i < 4; ++i)
                #pragma unroll
                for (int j = 0; j < 4; ++j)
                    acc[i][j] = __builtin_amdgcn_mfma_f32_16x16x32_bf16(af[i], bfr[j], acc[i][j], 0, 0, 0);
        }
    }

    #pragma unroll
    for (int j = 0; j < 4; ++j) {
        const int n = n0 + wn*64 + j*16 + lcol;
        const float bv = bias[n];
        #pragma unroll
        for (int i = 0; i < 4; ++i) {
            #pragma unroll
            for (int r = 0; r < 4; ++r) {
                const int m = m0 + wm*64 + i*16 + lgrp*4 + r;
                out[(size_t)m * C_ + n] = acc[i][j][r] + bv;
            }
        }
    }
}

// ---------------------------------------------------------------------------
extern "C" void kernel_launch(void* const* d_in, const int* in_sizes, int n_in,
                              void* d_out, int out_size, void* d_ws, size_t ws_size,
                              hipStream_t stream)
{
    const float* x      = (const float*)d_in[0];
    const float* w_qkv  = (const float*)d_in[1];
    const float* b_qkv  = (const float*)d_in[2];
    const float* w_proj = (const float*)d_in[3];
    const float* b_proj = (const float*)d_in[4];
    float* out = (float*)d_out;

    bf16_t* ws = (bf16_t*)d_ws;
    bf16_t* q  = ws;
    bf16_t* k  = ws + QKV_ELEMS;
    bf16_t* v  = ws + 2 * QKV_ELEMS;
    bf16_t* ao = ws + 3 * QKV_ELEMS;

    qkv_gemm<<<dim3(64 * 18), 256, 0, stream>>>(x, w_qkv, b_qkv, q, k, v);
    attn_fwd<<<dim3(48 * 32), 256, 0, stream>>>(q, k, v, ao);
    proj_gemm<<<dim3(64 * 6), 256, 0, stream>>>(ao, w_proj, b_proj, out);
}

// Round 2
// 158.806 us; speedup vs baseline: 2.2183x; 2.2183x over previous
//
#include <hip/hip_runtime.h>
#include <hip/hip_bf16.h>
#include <cstdint>
#include <cstddef>

typedef __bf16 bf16_t;
typedef __bf16 bf16x8 __attribute__((ext_vector_type(8)));
typedef __bf16 bf16x4 __attribute__((ext_vector_type(4)));
typedef float f32x4 __attribute__((ext_vector_type(4)));
typedef float f32x16 __attribute__((ext_vector_type(16)));

constexpr int B_ = 4, T_ = 2048, C_ = 768, H_ = 12, D_ = 64;
constexpr size_t QKV_ELEMS = (size_t)B_ * H_ * T_ * D_;  // 6291456 per tensor

// ---------------------------------------------------------------------------
// Kernel 1: QKV GEMM.  C[m][n] = sum_k x[m][k]*w_qkv[n][k] + b[n]
// scattered into q/k/v laid out (B, H, T, D) as bf16.
// ---------------------------------------------------------------------------
__global__ __launch_bounds__(256, 2)
void qkv_gemm(const float* __restrict__ x, const float* __restrict__ wq,
              const float* __restrict__ bias,
              bf16_t* __restrict__ q, bf16_t* __restrict__ k, bf16_t* __restrict__ v)
{
    __shared__ alignas(16) bf16_t As[128 * 72];
    __shared__ alignas(16) bf16_t Bs[128 * 72];
    const int tid  = threadIdx.x;
    const int lane = tid & 63;
    const int wid  = tid >> 6;
    const int wm = wid >> 1, wn = wid & 1;
    const int bm = blockIdx.x & 63;   // 64 m-blocks
    const int bn = blockIdx.x >> 6;   // 18 n-blocks
    const int m0 = bm * 128, n0 = bn * 128;
    const int sr = tid >> 3, sc = tid & 7;
    const int lcol = lane & 15, lgrp = lane >> 4;

    f32x4 acc[4][4] = {};

    for (int kt = 0; kt < C_; kt += 64) {
        __syncthreads();
        #pragma unroll
        for (int p = 0; p < 4; ++p) {
            const int row = p * 32 + sr;
            const float4* ga = reinterpret_cast<const float4*>(x + (size_t)(m0 + row) * C_ + kt + sc * 8);
            float4 f0 = ga[0], f1 = ga[1];
            bf16x8 ta;
            ta[0]=(bf16_t)f0.x; ta[1]=(bf16_t)f0.y; ta[2]=(bf16_t)f0.z; ta[3]=(bf16_t)f0.w;
            ta[4]=(bf16_t)f1.x; ta[5]=(bf16_t)f1.y; ta[6]=(bf16_t)f1.z; ta[7]=(bf16_t)f1.w;
            *reinterpret_cast<bf16x8*>(&As[row * 72 + sc * 8]) = ta;
            const float4* gb = reinterpret_cast<const float4*>(wq + (size_t)(n0 + row) * C_ + kt + sc * 8);
            float4 g0 = gb[0], g1 = gb[1];
            bf16x8 tb;
            tb[0]=(bf16_t)g0.x; tb[1]=(bf16_t)g0.y; tb[2]=(bf16_t)g0.z; tb[3]=(bf16_t)g0.w;
            tb[4]=(bf16_t)g1.x; tb[5]=(bf16_t)g1.y; tb[6]=(bf16_t)g1.z; tb[7]=(bf16_t)g1.w;
            *reinterpret_cast<bf16x8*>(&Bs[row * 72 + sc * 8]) = tb;
        }
        __syncthreads();
        #pragma unroll
        for (int kk = 0; kk < 2; ++kk) {
            bf16x8 af[4], bfr[4];
            #pragma unroll
            for (int i = 0; i < 4; ++i)
                af[i] = *reinterpret_cast<const bf16x8*>(&As[(wm*64 + i*16 + lcol) * 72 + kk*32 + lgrp*8]);
            #pragma unroll
            for (int j = 0; j < 4; ++j)
                bfr[j] = *reinterpret_cast<const bf16x8*>(&Bs[(wn*64 + j*16 + lcol) * 72 + kk*32 + lgrp*8]);
            #pragma unroll
            for (int i = 0; i < 4; ++i)
                #pragma unroll
                for (int j = 0; j < 4; ++j)
                    acc[i][j] = __builtin_amdgcn_mfma_f32_16x16x32_bf16(af[i], bfr[j], acc[i][j], 0, 0, 0);
        }
    }

    #pragma unroll
    for (int j = 0; j < 4; ++j) {
        const int n = n0 + wn*64 + j*16 + lcol;
        const float bv = bias[n];
        const int s = n / C_, rem = n % C_;
        const int h = rem >> 6, d = rem & 63;
        bf16_t* dst = (s == 0) ? q : (s == 1) ? k : v;
        #pragma unroll
        for (int i = 0; i < 4; ++i) {
            #pragma unroll
            for (int r = 0; r < 4; ++r) {
                const int m = m0 + wm*64 + i*16 + lgrp*4 + r;
                const int b = m >> 11, t = m & (T_ - 1);
                dst[(((size_t)(b * H_ + h)) * T_ + t) * D_ + d] = (bf16_t)(acc[i][j][r] + bv);
            }
        }
    }
}

// ---------------------------------------------------------------------------
// Kernel 2: causal flash attention, swapped-operand 32x32 structure.
// 4 waves/block, each wave owns 32 q-rows (128 q/block), KV tile = 64 keys.
// QK^T: mfma(K, Q) -> S^T[key][q], lane holds 16 scores of one q-row.
// Softmax lane-local (+1 shfl_xor(32)); P repacked via cvt_pk+permlane32_swap.
// PV:  mfma(V^T, P^T) -> O^T[d][q], col=q matches softmax state.
// K/Vt LDS XOR-swizzled (16B slot ^ row&7 [^ d>>3 for Vt]) -> bank-floor reads.
// ---------------------------------------------------------------------------
__global__ __launch_bounds__(256, 2)
void attn_fwd(const bf16_t* __restrict__ qg, const bf16_t* __restrict__ kg,
              const bf16_t* __restrict__ vg, bf16_t* __restrict__ og)
{
    __shared__ alignas(16) bf16_t Ks[64 * 64];  // [key][d], slot ^= key&7
    __shared__ alignas(16) bf16_t Vt[64 * 64];  // [d][key], slot ^= (d&7)^(d>>3)

    const int tid  = threadIdx.x;
    const int lane = tid & 63;
    const int w    = tid >> 6;
    const int l31  = lane & 31;
    const int hi   = lane >> 5;
    const int qi   = blockIdx.x / 48;
    const int bh   = blockIdx.x % 48;        // bh minor: same bh -> same XCD (48%8==0)
    const int qt   = 15 - qi;                // heavy blocks first
    const int q0   = qt * 128;
    const int qw   = q0 + w * 32;
    const size_t base = (size_t)bh * T_ * D_;
    const int qrow = qw + l31;

    // Q fragments (B-operand of swapped QK), prescaled by 0.125*log2(e)
    const float SCL = 0.125f * 1.44269504f;
    bf16x8 bq[4];
    #pragma unroll
    for (int kt = 0; kt < 4; ++kt) {
        bf16x8 t = *reinterpret_cast<const bf16x8*>(qg + base + (size_t)qrow * D_ + kt*16 + hi*8);
        #pragma unroll
        for (int e = 0; e < 8; ++e) t[e] = (bf16_t)((float)t[e] * SCL);
        bq[kt] = t;
    }

    f32x16 ot0 = {};
    f32x16 ot1 = {};
    float m = -1e30f, rowl = 0.0f;

    const int ntiles = qt * 2 + 2;
    for (int it = 0; it < ntiles; ++it) {
        const int kv0 = it * 64;
        __syncthreads();
        // stage K [64 keys][64 d], 16B granules, slot ^= key&7
        #pragma unroll
        for (int p = 0; p < 2; ++p) {
            const int g = p * 256 + tid;
            const int key = g >> 3, slot = g & 7;
            bf16x8 val = *reinterpret_cast<const bf16x8*>(kg + base + (size_t)(kv0 + key) * D_ + slot * 8);
            *reinterpret_cast<bf16x8*>(Ks + key * 64 + ((slot ^ (key & 7)) << 3)) = val;
        }
        // stage V transposed [64 d][64 keys], key-slot ^= (d&7)^(d>>3)
        #pragma unroll
        for (int p = 0; p < 2; ++p) {
            const int g = p * 256 + tid;
            const int key = g >> 3, dc = g & 7;   // dc fastest -> coalesced global reads
            bf16x8 val = *reinterpret_cast<const bf16x8*>(vg + base + (size_t)(kv0 + key) * D_ + dc * 8);
            #pragma unroll
            for (int j = 0; j < 8; ++j) {
                const int d = dc * 8 + j;
                Vt[d * 64 + ((((key >> 3) ^ (d & 7) ^ dc) & 7) << 3) + (key & 7)] = val[j];
            }
        }
        __syncthreads();

        #pragma unroll
        for (int sk = 0; sk < 2; ++sk) {
            const int kvs = kv0 + sk * 32;
            if (kvs > qw + 31) continue;   // wave-uniform skip

            // S^T = K · Q  (32 keys x 32 q), accumulate over D=64
            f32x16 s = {};
            #pragma unroll
            for (int kt = 0; kt < 4; ++kt) {
                const int keyl = sk * 32 + l31;
                const int slot = kt * 2 + hi;
                bf16x8 ka = *reinterpret_cast<const bf16x8*>(Ks + keyl * 64 + ((slot ^ (keyl & 7)) << 3));
                s = __builtin_amdgcn_mfma_f32_32x32x16_bf16(ka, bq[kt], s, 0, 0, 0);
            }
            // causal mask (only boundary subtile)
            if (kvs + 31 > qw) {
                #pragma unroll
                for (int r = 0; r < 16; ++r) {
                    const int key = kvs + (r & 3) + 8 * (r >> 2) + 4 * hi;
                    if (key > qrow) s[r] = -1e30f;
                }
            }
            // lane-local online softmax (log2 domain), q = l31 owned by lane pair
            float mt = s[0];
            #pragma unroll
            for (int r = 1; r < 16; ++r) mt = fmaxf(mt, s[r]);
            mt = fmaxf(mt, __shfl_xor(mt, 32));
            if (!__all(mt <= m + 8.0f)) {   // defer-max (T13)
                const float mnew = fmaxf(m, mt);
                const float alpha = exp2f(m - mnew);
                #pragma unroll
                for (int r = 0; r < 16; ++r) { ot0[r] *= alpha; ot1[r] *= alpha; }
                rowl *= alpha;
                m = mnew;
            }
            float pv[16];
            float rs = 0.0f;
            #pragma unroll
            for (int r = 0; r < 16; ++r) { pv[r] = exp2f(s[r] - m); rs += pv[r]; }
            rs += __shfl_xor(rs, 32);
            rowl += rs;

            // pack P -> bf16 B-fragments via cvt_pk + permlane32_swap (T12)
            uint32_t c0, c1, c2, c3, c4, c5, c6, c7;
            asm("v_cvt_pk_bf16_f32 %0, %1, %2" : "=v"(c0) : "v"(pv[0]),  "v"(pv[1]));
            asm("v_cvt_pk_bf16_f32 %0, %1, %2" : "=v"(c1) : "v"(pv[2]),  "v"(pv[3]));
            asm("v_cvt_pk_bf16_f32 %0, %1, %2" : "=v"(c2) : "v"(pv[4]),  "v"(pv[5]));
            asm("v_cvt_pk_bf16_f32 %0, %1, %2" : "=v"(c3) : "v"(pv[6]),  "v"(pv[7]));
            asm("v_cvt_pk_bf16_f32 %0, %1, %2" : "=v"(c4) : "v"(pv[8]),  "v"(pv[9]));
            asm("v_cvt_pk_bf16_f32 %0, %1, %2" : "=v"(c5) : "v"(pv[10]), "v"(pv[11]));
            asm("v_cvt_pk_bf16_f32 %0, %1, %2" : "=v"(c6) : "v"(pv[12]), "v"(pv[13]));
            asm("v_cvt_pk_bf16_f32 %0, %1, %2" : "=v"(c7) : "v"(pv[14]), "v"(pv[15]));
            asm("v_permlane32_swap_b32 %0, %1" : "+v"(c0), "+v"(c2));
            asm("v_permlane32_swap_b32 %0, %1" : "+v"(c1), "+v"(c3));
            asm("v_permlane32_swap_b32 %0, %1" : "+v"(c4), "+v"(c6));
            asm("v_permlane32_swap_b32 %0, %1" : "+v"(c5), "+v"(c7));
            union U { uint32_t u[4]; bf16x8 v; };
            U pa0; pa0.u[0] = c0; pa0.u[1] = c1; pa0.u[2] = c2; pa0.u[3] = c3;
            U pa1; pa1.u[0] = c4; pa1.u[1] = c5; pa1.u[2] = c6; pa1.u[3] = c7;

            // O^T += V^T · P^T   (two d-blocks of 32, two 16-key k-tiles)
            #pragma unroll
            for (int dblk = 0; dblk < 2; ++dblk) {
                const int d = dblk * 32 + l31;
                f32x16& o = dblk ? ot1 : ot0;
                #pragma unroll
                for (int ktile = 0; ktile < 2; ++ktile) {
                    const int kslot = sk * 4 + ktile * 2 + hi;
                    const int ss = kslot ^ (d & 7) ^ ((d >> 3) & 7);
                    bf16x8 va = *reinterpret_cast<const bf16x8*>(Vt + d * 64 + (ss << 3));
                    o = __builtin_amdgcn_mfma_f32_32x32x16_bf16(va, ktile ? pa1.v : pa0.v, o, 0, 0, 0);
                }
            }
        }
    }

    // epilogue: O^T[d][q] / rowl -> og (B,T,C) bf16
    const int b = bh / H_, h = bh % H_;
    const float inv = 1.0f / rowl;
    bf16_t* dst = &og[((size_t)b * T_ + qrow) * C_ + h * D_];
    #pragma unroll
    for (int dblk = 0; dblk < 2; ++dblk) {
        const f32x16& o = dblk ? ot1 : ot0;
        #pragma unroll
        for (int qd = 0; qd < 4; ++qd) {
            bf16x4 v4;
            #pragma unroll
            for (int r = 0; r < 4; ++r) v4[r] = (bf16_t)(o[qd * 4 + r] * inv);
            *reinterpret_cast<bf16x4*>(dst + dblk * 32 + qd * 8 + hi * 4) = v4;
        }
    }
}

// ---------------------------------------------------------------------------
// Kernel 3: output projection.  out[m][n] = sum_k ao[m][k]*w_proj[n][k] + b[n]
// ---------------------------------------------------------------------------
__global__ __launch_bounds__(256, 2)
void proj_gemm(const bf16_t* __restrict__ ao, const float* __restrict__ wp,
               const float* __restrict__ bias, float* __restrict__ out)
{
    __shared__ alignas(16) bf16_t As[128 * 72];
    __shared__ alignas(16) bf16_t Bs[128 * 72];
    const int tid  = threadIdx.x;
    const int lane = tid & 63;
    const int wid  = tid >> 6;
    const int wm = wid >> 1, wn = wid & 1;
    const int bm = blockIdx.x & 63;   // 64 m-blocks
    const int bn = blockIdx.x >> 6;   // 6 n-blocks
    const int m0 = bm * 128, n0 = bn * 128;
    const int lcol = lane & 15, lgrp = lane >> 4;

    f32x4 acc[4][4] = {};

    for (int kt = 0; kt < C_; kt += 64) {
        __syncthreads();
        #pragma unroll
        for (int p = 0; p < 4; ++p) {
            const int row = p * 32 + (tid >> 3);
            const int cs  = tid & 7;
            *reinterpret_cast<bf16x8*>(&As[row * 72 + cs * 8]) =
                *reinterpret_cast<const bf16x8*>(&ao[(size_t)(m0 + row) * C_ + kt + cs * 8]);
            const float4* gb = reinterpret_cast<const float4*>(wp + (size_t)(n0 + row) * C_ + kt + cs * 8);
            float4 g0 = gb[0], g1 = gb[1];
            bf16x8 tb;
            tb[0]=(bf16_t)g0.x; tb[1]=(bf16_t)g0.y; tb[2]=(bf16_t)g0.z; tb[3]=(bf16_t)g0.w;
            tb[4]=(bf16_t)g1.x; tb[5]=(bf16_t)g1.y; tb[6]=(bf16_t)g1.z; tb[7]=(bf16_t)g1.w;
            *reinterpret_cast<bf16x8*>(&Bs[row * 72 + cs * 8]) = tb;
        }
        __syncthreads();
        #pragma unroll
        for (int kk = 0; kk < 2; ++kk) {
            bf16x8 af[4], bfr[4];
            #pragma unroll
            for (int i = 0; i < 4; ++i)
                af[i] = *reinterpret_cast<const bf16x8*>(&As[(wm*64 + i*16 + lcol) * 72 + kk*32 + lgrp*8]);
            #pragma unroll
            for (int j = 0; j < 4; ++j)
                bfr[j] = *reinterpret_cast<const bf16x8*>(&Bs[(wn*64 + j*16 + lcol) * 72 + kk*32 + lgrp*8]);
            #pragma unroll
            for (int i = 0; i < 4; ++i)
                #pragma unroll
                for (int j = 0; j < 4; ++j)
                    acc[i][j] = __builtin_amdgcn_mfma_f32_16x16x32_bf16(af[i], bfr[j], acc[i][j], 0, 0, 0);
        }
    }

    #pragma unroll
    for (int j = 0; j < 4; ++j) {
        const int n = n0 + wn*64 + j*16 + lcol;
        const float bv = bias[n];
        #pragma unroll
        for (int i = 0; i < 4; ++i) {
            #pragma unroll
            for (int r = 0; r < 4; ++r) {
                const int m = m0 + wm*64 + i*16 + lgrp*4 + r;
                out[(size_t)m * C_ + n] = acc[i][j][r] + bv;
            }
        }
    }
}

// ---------------------------------------------------------------------------
extern "C" void kernel_launch(void* const* d_in, const int* in_sizes, int n_in,
                              void* d_out, int out_size, void* d_ws, size_t ws_size,
                              hipStream_t stream)
{
    const float* x      = (const float*)d_in[0];
    const float* w_qkv  = (const float*)d_in[1];
    const float* b_qkv  = (const float*)d_in[2];
    const float* w_proj = (const float*)d_in[3];
    const float* b_proj = (const float*)d_in[4];
    float* out = (float*)d_out;

    bf16_t* ws = (bf16_t*)d_ws;
    bf16_t* q  = ws;
    bf16_t* k  = ws + QKV_ELEMS;
    bf16_t* v  = ws + 2 * QKV_ELEMS;
    bf16_t* ao = ws + 3 * QKV_ELEMS;

    qkv_gemm<<<dim3(64 * 18), 256, 0, stream>>>(x, w_qkv, b_qkv, q, k, v);
    attn_fwd<<<dim3(16 * 48), 256, 0, stream>>>(q, k, v, ao);
    proj_gemm<<<dim3(64 * 6), 256, 0, stream>>>(ao, w_proj, b_proj, out);
}

// Round 3
// 122.395 us; speedup vs baseline: 2.8782x; 1.2975x over previous
//
#include <hip/hip_runtime.h>
#include <hip/hip_bf16.h>
#include <cstdint>
#include <cstddef>

typedef __bf16 bf16_t;
typedef __bf16 bf16x8 __attribute__((ext_vector_type(8)));
typedef __bf16 bf16x4 __attribute__((ext_vector_type(4)));
typedef float f32x4 __attribute__((ext_vector_type(4)));
typedef float f32x16 __attribute__((ext_vector_type(16)));

constexpr int B_ = 4, T_ = 2048, C_ = 768, H_ = 12, D_ = 64;
constexpr size_t QKV_ELEMS = (size_t)B_ * H_ * T_ * D_;  // 6291456 per tensor

__device__ __forceinline__ void gload16(const bf16_t* g, bf16_t* l) {
    __builtin_amdgcn_global_load_lds(
        (const __attribute__((address_space(1))) unsigned int*)g,
        (__attribute__((address_space(3))) unsigned int*)l, 16, 0, 0);
}

// ---------------------------------------------------------------------------
// Streaming fp32 -> bf16 convert (two buffers in one launch).
// ---------------------------------------------------------------------------
__global__ __launch_bounds__(256)
void conv_bf16(const float* __restrict__ a, bf16_t* __restrict__ oa, int na8,
               const float* __restrict__ b, bf16_t* __restrict__ ob, int nb8)
{
    int i = blockIdx.x * 256 + threadIdx.x;
    if (i >= na8 + nb8) return;
    const float* src; bf16_t* dst; int idx;
    if (i < na8) { src = a; dst = oa; idx = i; }
    else         { src = b; dst = ob; idx = i - na8; }
    const float4* p = reinterpret_cast<const float4*>(src + (size_t)idx * 8);
    float4 f0 = p[0], f1 = p[1];
    bf16x8 t;
    t[0]=(bf16_t)f0.x; t[1]=(bf16_t)f0.y; t[2]=(bf16_t)f0.z; t[3]=(bf16_t)f0.w;
    t[4]=(bf16_t)f1.x; t[5]=(bf16_t)f1.y; t[6]=(bf16_t)f1.z; t[7]=(bf16_t)f1.w;
    *reinterpret_cast<bf16x8*>(dst + (size_t)idx * 8) = t;
}

// ---------------------------------------------------------------------------
// Kernel 1: QKV GEMM, m97 structure: bf16 inputs, global_load_lds(16B),
// linear LDS [128][64] with XOR-preswizzled source granules.
// C[m][n] = sum_k xb[m][k]*wb[n][k], + bias, scatter to q/k/v (B,H,T,D) bf16.
// ---------------------------------------------------------------------------
__global__ __launch_bounds__(256, 3)
void qkv_gemm(const bf16_t* __restrict__ xb, const bf16_t* __restrict__ wb,
              const float* __restrict__ bias,
              bf16_t* __restrict__ q, bf16_t* __restrict__ k, bf16_t* __restrict__ v)
{
    __shared__ alignas(16) bf16_t As[128 * 64];
    __shared__ alignas(16) bf16_t Bs[128 * 64];
    const int tid  = threadIdx.x;
    const int lane = tid & 63;
    const int w    = tid >> 6;
    const int wm = w >> 1, wn = w & 1;
    const int bm = blockIdx.x & 63;   // 64 m-blocks
    const int bn = blockIdx.x >> 6;   // 18 n-blocks
    const int m0 = bm * 128, n0 = bn * 128;
    const int lcol = lane & 15, lgrp = lane >> 4;
    const int srow = lane >> 3;             // 0..7 row within issue octet
    const int scol = ((lane & 7) ^ srow) * 8;  // pre-swizzled source granule

    const bf16_t* ag = xb + (size_t)(m0 + w * 32 + srow) * C_ + scol;
    const bf16_t* bg = wb + (size_t)(n0 + w * 32 + srow) * C_ + scol;
    bf16_t* al = &As[(w * 32) * 64];
    bf16_t* bl = &Bs[(w * 32) * 64];

    f32x4 acc[4][4] = {};

    for (int kt = 0; kt < C_; kt += 64) {
        __syncthreads();
        #pragma unroll
        for (int p = 0; p < 4; ++p) {
            gload16(ag + (size_t)(p * 8) * C_ + kt, al + p * 8 * 64);
            gload16(bg + (size_t)(p * 8) * C_ + kt, bl + p * 8 * 64);
        }
        __syncthreads();
        #pragma unroll
        for (int kk = 0; kk < 2; ++kk) {
            bf16x8 af[4], bfr[4];
            #pragma unroll
            for (int i = 0; i < 4; ++i) {
                const int R = wm * 64 + i * 16 + lcol;
                af[i] = *reinterpret_cast<const bf16x8*>(&As[R * 64 + (((kk*4 + lgrp) ^ (R & 7)) << 3)]);
            }
            #pragma unroll
            for (int j = 0; j < 4; ++j) {
                const int R = wn * 64 + j * 16 + lcol;
                bfr[j] = *reinterpret_cast<const bf16x8*>(&Bs[R * 64 + (((kk*4 + lgrp) ^ (R & 7)) << 3)]);
            }
            #pragma unroll
            for (int i = 0; i < 4; ++i)
                #pragma unroll
                for (int j = 0; j < 4; ++j)
                    acc[i][j] = __builtin_amdgcn_mfma_f32_16x16x32_bf16(af[i], bfr[j], acc[i][j], 0, 0, 0);
        }
    }

    #pragma unroll
    for (int j = 0; j < 4; ++j) {
        const int n = n0 + wn * 64 + j * 16 + lcol;
        const float bv = bias[n];
        const int s = n / C_, rem = n % C_;
        const int h = rem >> 6, d = rem & 63;
        bf16_t* dst = (s == 0) ? q : (s == 1) ? k : v;
        #pragma unroll
        for (int i = 0; i < 4; ++i) {
            #pragma unroll
            for (int r = 0; r < 4; ++r) {
                const int m = m0 + wm * 64 + i * 16 + lgrp * 4 + r;
                const int b = m >> 11, t = m & (T_ - 1);
                dst[(((size_t)(b * H_ + h)) * T_ + t) * D_ + d] = (bf16_t)(acc[i][j][r] + bv);
            }
        }
    }
}

// ---------------------------------------------------------------------------
// Kernel 2: causal flash attention, swapped-operand 32x32 structure +
// async-STAGE split double buffering (T14) + setprio around MFMA (T5).
// ---------------------------------------------------------------------------
__global__ __launch_bounds__(256, 2)
void attn_fwd(const bf16_t* __restrict__ qg, const bf16_t* __restrict__ kg,
              const bf16_t* __restrict__ vg, bf16_t* __restrict__ og)
{
    __shared__ alignas(16) bf16_t Ks[64 * 64];  // [key][d], slot ^= key&7
    __shared__ alignas(16) bf16_t Vt[64 * 64];  // [d][key], slot ^= (d&7)^(d>>3)

    const int tid  = threadIdx.x;
    const int lane = tid & 63;
    const int w    = tid >> 6;
    const int l31  = lane & 31;
    const int hi   = lane >> 5;
    const int qi   = blockIdx.x / 48;
    const int bh   = blockIdx.x % 48;        // bh minor: same bh -> same XCD (48%8==0)
    const int qt   = 15 - qi;                // heavy blocks first
    const int q0   = qt * 128;
    const int qw   = q0 + w * 32;
    const size_t base = (size_t)bh * T_ * D_;
    const int qrow = qw + l31;

    const float SCL = 0.125f * 1.44269504f;  // scale * log2(e)
    bf16x8 bq[4];
    #pragma unroll
    for (int kt = 0; kt < 4; ++kt) {
        bf16x8 t = *reinterpret_cast<const bf16x8*>(qg + base + (size_t)qrow * D_ + kt*16 + hi*8);
        #pragma unroll
        for (int e = 0; e < 8; ++e) t[e] = (bf16_t)((float)t[e] * SCL);
        bq[kt] = t;
    }

    f32x16 ot0 = {};
    f32x16 ot1 = {};
    float m = -1e30f, rowl = 0.0f;

    const int skey = tid >> 3;        // staging key 0..31 (+p*32)
    const int sgr  = tid & 7;         // staging granule
    bf16x8 kr[2], vr[2];

    // prologue: prefetch tile 0 into regs
    #pragma unroll
    for (int p = 0; p < 2; ++p) {
        const int key = p * 32 + skey;
        kr[p] = *reinterpret_cast<const bf16x8*>(kg + base + (size_t)key * D_ + sgr * 8);
        vr[p] = *reinterpret_cast<const bf16x8*>(vg + base + (size_t)key * D_ + sgr * 8);
    }

    const int ntiles = qt * 2 + 2;
    for (int it = 0; it < ntiles; ++it) {
        __syncthreads();    // previous tile's compute done -> LDS free
        // write prefetched regs -> LDS
        #pragma unroll
        for (int p = 0; p < 2; ++p) {
            const int key = p * 32 + skey;
            *reinterpret_cast<bf16x8*>(Ks + key * 64 + ((sgr ^ (key & 7)) << 3)) = kr[p];
            #pragma unroll
            for (int j = 0; j < 8; ++j) {
                const int d = sgr * 8 + j;
                Vt[d * 64 + ((((key >> 3) ^ (d & 7) ^ sgr) & 7) << 3) + (key & 7)] = vr[p][j];
            }
        }
        __syncthreads();    // LDS ready
        // issue next tile's global loads (latency hides under compute)
        if (it + 1 < ntiles) {
            const int kvn = (it + 1) * 64;
            #pragma unroll
            for (int p = 0; p < 2; ++p) {
                const int key = kvn + p * 32 + skey;
                kr[p] = *reinterpret_cast<const bf16x8*>(kg + base + (size_t)key * D_ + sgr * 8);
                vr[p] = *reinterpret_cast<const bf16x8*>(vg + base + (size_t)key * D_ + sgr * 8);
            }
        }

        const int kv0 = it * 64;
        #pragma unroll
        for (int sk = 0; sk < 2; ++sk) {
            const int kvs = kv0 + sk * 32;
            if (kvs > qw + 31) continue;   // wave-uniform skip

            // S^T = K . Q  (32 keys x 32 q), accumulate over D=64
            f32x16 s = {};
            __builtin_amdgcn_s_setprio(1);
            #pragma unroll
            for (int kt = 0; kt < 4; ++kt) {
                const int keyl = sk * 32 + l31;
                const int slot = kt * 2 + hi;
                bf16x8 ka = *reinterpret_cast<const bf16x8*>(Ks + keyl * 64 + ((slot ^ (keyl & 7)) << 3));
                s = __builtin_amdgcn_mfma_f32_32x32x16_bf16(ka, bq[kt], s, 0, 0, 0);
            }
            __builtin_amdgcn_s_setprio(0);
            // causal mask (boundary subtile only)
            if (kvs + 31 > qw) {
                #pragma unroll
                for (int r = 0; r < 16; ++r) {
                    const int key = kvs + (r & 3) + 8 * (r >> 2) + 4 * hi;
                    if (key > qrow) s[r] = -1e30f;
                }
            }
            // lane-local online softmax (log2 domain)
            float mt = s[0];
            #pragma unroll
            for (int r = 1; r < 16; ++r) mt = fmaxf(mt, s[r]);
            mt = fmaxf(mt, __shfl_xor(mt, 32));
            if (!__all(mt <= m + 8.0f)) {   // defer-max (T13)
                const float mnew = fmaxf(m, mt);
                const float alpha = exp2f(m - mnew);
                #pragma unroll
                for (int r = 0; r < 16; ++r) { ot0[r] *= alpha; ot1[r] *= alpha; }
                rowl *= alpha;
                m = mnew;
            }
            float pv[16];
            float rs = 0.0f;
            #pragma unroll
            for (int r = 0; r < 16; ++r) { pv[r] = exp2f(s[r] - m); rs += pv[r]; }
            rs += __shfl_xor(rs, 32);
            rowl += rs;

            // pack P -> bf16 B-fragments via cvt_pk + permlane32_swap (T12)
            uint32_t c0, c1, c2, c3, c4, c5, c6, c7;
            asm("v_cvt_pk_bf16_f32 %0, %1, %2" : "=v"(c0) : "v"(pv[0]),  "v"(pv[1]));
            asm("v_cvt_pk_bf16_f32 %0, %1, %2" : "=v"(c1) : "v"(pv[2]),  "v"(pv[3]));
            asm("v_cvt_pk_bf16_f32 %0, %1, %2" : "=v"(c2) : "v"(pv[4]),  "v"(pv[5]));
            asm("v_cvt_pk_bf16_f32 %0, %1, %2" : "=v"(c3) : "v"(pv[6]),  "v"(pv[7]));
            asm("v_cvt_pk_bf16_f32 %0, %1, %2" : "=v"(c4) : "v"(pv[8]),  "v"(pv[9]));
            asm("v_cvt_pk_bf16_f32 %0, %1, %2" : "=v"(c5) : "v"(pv[10]), "v"(pv[11]));
            asm("v_cvt_pk_bf16_f32 %0, %1, %2" : "=v"(c6) : "v"(pv[12]), "v"(pv[13]));
            asm("v_cvt_pk_bf16_f32 %0, %1, %2" : "=v"(c7) : "v"(pv[14]), "v"(pv[15]));
            asm("v_permlane32_swap_b32 %0, %1" : "+v"(c0), "+v"(c2));
            asm("v_permlane32_swap_b32 %0, %1" : "+v"(c1), "+v"(c3));
            asm("v_permlane32_swap_b32 %0, %1" : "+v"(c4), "+v"(c6));
            asm("v_permlane32_swap_b32 %0, %1" : "+v"(c5), "+v"(c7));
            union U { uint32_t u[4]; bf16x8 v; };
            U pa0; pa0.u[0] = c0; pa0.u[1] = c1; pa0.u[2] = c2; pa0.u[3] = c3;
            U pa1; pa1.u[0] = c4; pa1.u[1] = c5; pa1.u[2] = c6; pa1.u[3] = c7;

            // O^T += V^T . P^T
            __builtin_amdgcn_s_setprio(1);
            #pragma unroll
            for (int dblk = 0; dblk < 2; ++dblk) {
                const int d = dblk * 32 + l31;
                f32x16& o = dblk ? ot1 : ot0;
                #pragma unroll
                for (int ktile = 0; ktile < 2; ++ktile) {
                    const int kslot = sk * 4 + ktile * 2 + hi;
                    const int ss = kslot ^ (d & 7) ^ ((d >> 3) & 7);
                    bf16x8 va = *reinterpret_cast<const bf16x8*>(Vt + d * 64 + (ss << 3));
                    o = __builtin_amdgcn_mfma_f32_32x32x16_bf16(va, ktile ? pa1.v : pa0.v, o, 0, 0, 0);
                }
            }
            __builtin_amdgcn_s_setprio(0);
        }
    }

    // epilogue: O^T[d][q] / rowl -> og (B,T,C) bf16
    const int b = bh / H_, h = bh % H_;
    const float inv = 1.0f / rowl;
    bf16_t* dst = &og[((size_t)b * T_ + qrow) * C_ + h * D_];
    #pragma unroll
    for (int dblk = 0; dblk < 2; ++dblk) {
        const f32x16& o = dblk ? ot1 : ot0;
        #pragma unroll
        for (int qd = 0; qd < 4; ++qd) {
            bf16x4 v4;
            #pragma unroll
            for (int r = 0; r < 4; ++r) v4[r] = (bf16_t)(o[qd * 4 + r] * inv);
            *reinterpret_cast<bf16x4*>(dst + dblk * 32 + qd * 8 + hi * 4) = v4;
        }
    }
}

// ---------------------------------------------------------------------------
// Kernel 3: output projection, m97 structure. out fp32 = ao * wpb^T + bias.
// ---------------------------------------------------------------------------
__global__ __launch_bounds__(256, 3)
void proj_gemm(const bf16_t* __restrict__ ao, const bf16_t* __restrict__ wpb,
               const float* __restrict__ bias, float* __restrict__ out)
{
    __shared__ alignas(16) bf16_t As[128 * 64];
    __shared__ alignas(16) bf16_t Bs[128 * 64];
    const int tid  = threadIdx.x;
    const int lane = tid & 63;
    const int w    = tid >> 6;
    const int wm = w >> 1, wn = w & 1;
    const int bm = blockIdx.x & 63;   // 64 m-blocks
    const int bn = blockIdx.x >> 6;   // 6 n-blocks
    const int m0 = bm * 128, n0 = bn * 128;
    const int lcol = lane & 15, lgrp = lane >> 4;
    const int srow = lane >> 3;
    const int scol = ((lane & 7) ^ srow) * 8;

    const bf16_t* ag = ao  + (size_t)(m0 + w * 32 + srow) * C_ + scol;
    const bf16_t* bg = wpb + (size_t)(n0 + w * 32 + srow) * C_ + scol;
    bf16_t* al = &As[(w * 32) * 64];
    bf16_t* bl = &Bs[(w * 32) * 64];

    f32x4 acc[4][4] = {};

    for (int kt = 0; kt < C_; kt += 64) {
        __syncthreads();
        #pragma unroll
        for (int p = 0; p < 4; ++p) {
            gload16(ag + (size_t)(p * 8) * C_ + kt, al + p * 8 * 64);
            gload16(bg + (size_t)(p * 8) * C_ + kt, bl + p * 8 * 64);
        }
        __syncthreads();
        #pragma unroll
        for (int kk = 0; kk < 2; ++kk) {
            bf16x8 af[4], bfr[4];
            #pragma unroll
            for (int i = 0; i < 4; ++i) {
                const int R = wm * 64 + i * 16 + lcol;
                af[i] = *reinterpret_cast<const bf16x8*>(&As[R * 64 + (((kk*4 + lgrp) ^ (R & 7)) << 3)]);
            }
            #pragma unroll
            for (int j = 0; j < 4; ++j) {
                const int R = wn * 64 + j * 16 + lcol;
                bfr[j] = *reinterpret_cast<const bf16x8*>(&Bs[R * 64 + (((kk*4 + lgrp) ^ (R & 7)) << 3)]);
            }
            #pragma unroll
            for (int i = 0; i < 4; ++i)
                #pragma unroll
                for (int j = 0; j < 4; ++j)
                    acc[i][j] = __builtin_amdgcn_mfma_f32_16x16x32_bf16(af[i], bfr[j], acc[i][j], 0, 0, 0);
        }
    }

    #pragma unroll
    for (int j = 0; j < 4; ++j) {
        const int n = n0 + wn * 64 + j * 16 + lcol;
        const float bv = bias[n];
        #pragma unroll
        for (int i = 0; i < 4; ++i) {
            #pragma unroll
            for (int r = 0; r < 4; ++r) {
                const int m = m0 + wm * 64 + i * 16 + lgrp * 4 + r;
                out[(size_t)m * C_ + n] = acc[i][j][r] + bv;
            }
        }
    }
}

// ---------------------------------------------------------------------------
extern "C" void kernel_launch(void* const* d_in, const int* in_sizes, int n_in,
                              void* d_out, int out_size, void* d_ws, size_t ws_size,
                              hipStream_t stream)
{
    const float* x      = (const float*)d_in[0];
    const float* w_qkv  = (const float*)d_in[1];
    const float* b_qkv  = (const float*)d_in[2];
    const float* w_proj = (const float*)d_in[3];
    const float* b_proj = (const float*)d_in[4];
    float* out = (float*)d_out;

    bf16_t* ws = (bf16_t*)d_ws;
    bf16_t* q   = ws;
    bf16_t* k   = ws +     QKV_ELEMS;
    bf16_t* v   = ws + 2 * QKV_ELEMS;
    bf16_t* ao  = ws + 3 * QKV_ELEMS;
    bf16_t* xb  = ao;               // alias: dead once qkv_gemm completes
    bf16_t* wqb = (bf16_t*)d_out;   // alias: out written only by proj at the end
    bf16_t* wpb = k;                // alias: k dead after attn; converted just-in-time

    // x: 6291456 elems -> 786432 granules; w_qkv: 1769472 -> 221184
    conv_bf16<<<dim3(3936), 256, 0, stream>>>(x, xb, 786432, w_qkv, wqb, 221184);
    qkv_gemm<<<dim3(64 * 18), 256, 0, stream>>>(xb, wqb, b_qkv, q, k, v);
    attn_fwd<<<dim3(16 * 48), 256, 0, stream>>>(q, k, v, ao);
    // w_proj: 589824 elems -> 73728 granules
    conv_bf16<<<dim3(288), 256, 0, stream>>>(w_proj, wpb, 73728, w_proj, wpb, 0);
    proj_gemm<<<dim3(64 * 6), 256, 0, stream>>>(ao, wpb, b_proj, out);
}